// Round 2
// baseline (411.671 us; speedup 1.0000x reference)
//
#include <hip/hip_runtime.h>
#include <hip/hip_bf16.h>
#include <stdint.h>

#define B_ 2
#define S_ 2048
#define D_ 2048
#define H_ 8
#define DK_ 256
#define SCALE_ 0.0625f
#define NEG_ -1e9f

typedef __hip_bfloat16 bf16;
typedef __attribute__((ext_vector_type(4))) float f32x4;
typedef __attribute__((ext_vector_type(8))) short bf16x8;
typedef unsigned int u32;

__device__ inline void gload_lds16(const void* g, void* l) {
  __builtin_amdgcn_global_load_lds(
      (const __attribute__((address_space(1))) u32*)g,
      (__attribute__((address_space(3))) u32*)l, 16, 0, 0);
}

// ---------------- fp32 -> bf16 convert (vectorized) ----------------
__global__ void cvt_kernel(const float* __restrict__ in, bf16* __restrict__ out, int n4) {
  int i = blockIdx.x * 256 + threadIdx.x;
  if (i >= n4) return;
  float4 v = ((const float4*)in)[i];
  ushort4 o;
  o.x = __builtin_bit_cast(unsigned short, __float2bfloat16(v.x));
  o.y = __builtin_bit_cast(unsigned short, __float2bfloat16(v.y));
  o.z = __builtin_bit_cast(unsigned short, __float2bfloat16(v.z));
  o.w = __builtin_bit_cast(unsigned short, __float2bfloat16(v.w));
  ((ushort4*)out)[i] = o;
}

// ---------------- fused Q/K projection GEMM (m97 structure) ----------------
// C[M,N] = A[M,K] @ W[N,K]^T + bias, stored bf16. M=4096, N=K=2048.
__global__ __launch_bounds__(256, 2) void gemm_qk(
    const bf16* __restrict__ A,
    const bf16* __restrict__ W0, const float* __restrict__ b0, bf16* __restrict__ C0,
    const bf16* __restrict__ W1, const float* __restrict__ b1, bf16* __restrict__ C1) {
  const int N = D_, Kd = D_;
  const bf16* Bm = blockIdx.z ? W1 : W0;
  const float* bias = blockIdx.z ? b1 : b0;
  bf16* C = blockIdx.z ? C1 : C0;

  __shared__ bf16 As[128 * 64];
  __shared__ bf16 Bs[128 * 64];
  const int tid = threadIdx.x;
  const int lane = tid & 63;
  const int w = tid >> 6;
  const int wr = w >> 1, wc = w & 1;
  const int bm = blockIdx.y, bn = blockIdx.x;

  f32x4 acc[4][4] = {};
  const int l8r = lane >> 3;        // 0..7 row within 8-row chunk
  const int l8c = (lane & 7) * 8;   // k element offset (8 bf16 = 16B)

  for (int kt = 0; kt < Kd; kt += 64) {
#pragma unroll
    for (int cc = 0; cc < 4; ++cc) {
      int chunk = w * 4 + cc;                       // 0..15
      int rowa = bm * 128 + chunk * 8 + l8r;
      gload_lds16(A + (size_t)rowa * Kd + kt + l8c, (char*)As + chunk * 1024);
      int rowb = bn * 128 + chunk * 8 + l8r;
      gload_lds16(Bm + (size_t)rowb * Kd + kt + l8c, (char*)Bs + chunk * 1024);
    }
    __syncthreads();
#pragma unroll
    for (int kk = 0; kk < 2; ++kk) {
      const int kloc = kk * 32 + (lane >> 4) * 8;
      bf16x8 af[4], bfr[4];
#pragma unroll
      for (int mi = 0; mi < 4; ++mi) {
        int row = wr * 64 + mi * 16 + (lane & 15);
        af[mi] = *(const bf16x8*)&As[row * 64 + kloc];
      }
#pragma unroll
      for (int ni = 0; ni < 4; ++ni) {
        int row = wc * 64 + ni * 16 + (lane & 15);
        bfr[ni] = *(const bf16x8*)&Bs[row * 64 + kloc];
      }
#pragma unroll
      for (int mi = 0; mi < 4; ++mi)
#pragma unroll
        for (int ni = 0; ni < 4; ++ni)
          acc[mi][ni] = __builtin_amdgcn_mfma_f32_16x16x32_bf16(af[mi], bfr[ni], acc[mi][ni], 0, 0, 0);
    }
    __syncthreads();
  }
  // epilogue: C layout col=lane&15, row=(lane>>4)*4+r
#pragma unroll
  for (int ni = 0; ni < 4; ++ni) {
    int col = bn * 128 + wc * 64 + ni * 16 + (lane & 15);
    float bb = bias[col];
#pragma unroll
    for (int mi = 0; mi < 4; ++mi) {
      int rbase = bm * 128 + wr * 64 + mi * 16 + (lane >> 4) * 4;
#pragma unroll
      for (int r = 0; r < 4; ++r)
        C[(size_t)(rbase + r) * N + col] = __float2bfloat16(acc[mi][ni][r] + bb);
    }
  }
}

// ---------------- score kernel: score[b,h,i] = sum_j lrelu(q_i.k_j)*Wa[j] ----------------
// grid (16 i-tiles, 2 j-halves, 16 bh); 256 thr = 4 waves in 2x2 (64i x 64j each)
__global__ __launch_bounds__(256, 2) void score_kernel(
    const bf16* __restrict__ Q, const bf16* __restrict__ Kb,
    const float* __restrict__ Wa, float* __restrict__ score) {
  __shared__ bf16 Ks[128 * 256];  // 64KB, XOR-swizzled rows
  const int tid = threadIdx.x, lane = tid & 63, w = tid >> 6;
  const int wr = w >> 1, wc = w & 1;
  const int it = blockIdx.x;
  const int jh = blockIdx.y;
  const int bh = blockIdx.z;
  const int b = bh >> 3, h = bh & 7;

  const size_t base_bh = (size_t)b * S_ * D_ + (size_t)h * DK_;

  // Q fragments held in registers, reused over all j tiles
  bf16x8 qf[4][8];
#pragma unroll
  for (int mi = 0; mi < 4; ++mi) {
    int row = it * 128 + wr * 64 + mi * 16 + (lane & 15);
    const bf16* qp = Q + base_bh + (size_t)row * D_ + ((lane >> 4) * 8);
#pragma unroll
    for (int kc = 0; kc < 8; ++kc) qf[mi][kc] = *(const bf16x8*)(qp + kc * 32);
  }

  float psum[4][4] = {};
  const int stg_sub = lane >> 5;  // 0..1: row within 2-row staging chunk

  for (int jt0 = 0; jt0 < 8; ++jt0) {
    const int jt = jh * 8 + jt0;
    // stage K tile [128 rows x 256k], linear LDS dest, pre-swizzled global source
#pragma unroll
    for (int cc = 0; cc < 16; ++cc) {
      int chunk = w * 16 + cc;                 // 0..63 (1KB each)
      int r = chunk * 2 + stg_sub;             // tile row
      int gb = ((lane & 31) * 16) ^ ((r & 7) << 4);  // swizzled byte-in-row
      gload_lds16(Kb + base_bh + (size_t)(jt * 128 + r) * D_ + (gb >> 1),
                  (char*)Ks + chunk * 1024);
    }
    __syncthreads();
#pragma unroll
    for (int nj = 0; nj < 4; ++nj) {
      int jloc = wc * 64 + nj * 16 + (lane & 15);
      bf16x8 bfr[8];
#pragma unroll
      for (int kc = 0; kc < 8; ++kc) {
        int kbyte = (kc * 32 + ((lane >> 4) * 8)) * 2;
        int pb = jloc * 512 + (kbyte ^ ((jloc & 7) << 4));
        bfr[kc] = *(const bf16x8*)((const char*)Ks + pb);
      }
      f32x4 cf[4] = {};
#pragma unroll
      for (int kc = 0; kc < 8; ++kc)
#pragma unroll
        for (int mi = 0; mi < 4; ++mi)
          cf[mi] = __builtin_amdgcn_mfma_f32_16x16x32_bf16(qf[mi][kc], bfr[kc], cf[mi], 0, 0, 0);
      float wa = Wa[jt * 128 + jloc];
#pragma unroll
      for (int mi = 0; mi < 4; ++mi)
#pragma unroll
        for (int r = 0; r < 4; ++r) {
          float v = cf[mi][r];
          v = (v > 0.f) ? v : 0.1f * v;   // leaky_relu 0.1
          psum[mi][r] += v * wa;
        }
    }
    __syncthreads();
  }
  // reduce over the 16 lanes holding different j columns of the same rows
#pragma unroll
  for (int mi = 0; mi < 4; ++mi)
#pragma unroll
    for (int r = 0; r < 4; ++r) {
      float v = psum[mi][r];
      v += __shfl_xor(v, 1); v += __shfl_xor(v, 2);
      v += __shfl_xor(v, 4); v += __shfl_xor(v, 8);
      if ((lane & 15) == 0) {
        int row = it * 128 + wr * 64 + mi * 16 + ((lane >> 4) * 4) + r;
        atomicAdd(&score[(size_t)bh * S_ + row], v);
      }
    }
}

// ---------------- masked scaled softmax over tokens ----------------
__global__ __launch_bounds__(256) void softmax_kernel(
    const float* __restrict__ score, const int* __restrict__ xmask,
    const float* __restrict__ ba, float* __restrict__ attn) {
  const int bh = blockIdx.x, tid = threadIdx.x;
  const int lane = tid & 63, w = tid >> 6;
  __shared__ float redm[4], reds[4];
  const float ba0 = ba[0];
  float loc[8];
  float mx = -3.4e38f;
#pragma unroll
  for (int t = 0; t < 8; ++t) {
    int i = t * 256 + tid;
    float s = SCALE_ * (score[(size_t)bh * S_ + i] + ba0);
    if (xmask[i] != 0) s = NEG_;
    loc[t] = s;
    mx = fmaxf(mx, s);
  }
  for (int m = 1; m < 64; m <<= 1) mx = fmaxf(mx, __shfl_xor(mx, m));
  if (lane == 0) redm[w] = mx;
  __syncthreads();
  mx = fmaxf(fmaxf(redm[0], redm[1]), fmaxf(redm[2], redm[3]));
  float sum = 0.f;
#pragma unroll
  for (int t = 0; t < 8; ++t) {
    loc[t] = expf(loc[t] - mx);
    sum += loc[t];
  }
  for (int m = 1; m < 64; m <<= 1) sum += __shfl_xor(sum, m);
  if (lane == 0) reds[w] = sum;
  __syncthreads();
  sum = reds[0] + reds[1] + reds[2] + reds[3];
  const float inv = 1.f / sum;
#pragma unroll
  for (int t = 0; t < 8; ++t) attn[(size_t)bh * S_ + t * 256 + tid] = loc[t] * inv;
}

// ---------------- xbar[b,h,c] = sum_s attn[b,h,s] * x[b,s,c] ----------------
// grid (8 c-chunks, 4 s-chunks, B)
__global__ __launch_bounds__(256) void xbar_kernel(
    const float* __restrict__ x, const float* __restrict__ attn, float* __restrict__ xbar) {
  const int cchunk = blockIdx.x, sc = blockIdx.y, b = blockIdx.z;
  const int tid = threadIdx.x;
  const int c = cchunk * 256 + tid;
  __shared__ float at_s[8][512];
  for (int i = tid; i < 8 * 512; i += 256) {
    int h = i >> 9, s = i & 511;
    at_s[h][s] = attn[((size_t)b * H_ + h) * S_ + sc * 512 + s];
  }
  __syncthreads();
  float acc[8] = {};
  const float* xp = x + ((size_t)b * S_ + sc * 512) * D_ + c;
  for (int s = 0; s < 512; ++s) {
    float xv = xp[(size_t)s * D_];
#pragma unroll
    for (int h = 0; h < 8; ++h) acc[h] += at_s[h][s] * xv;
  }
#pragma unroll
  for (int h = 0; h < 8; ++h) atomicAdd(&xbar[((size_t)b * H_ + h) * D_ + c], acc[h]);
}

// ---------------- pooled[b,dv] = xbar[b,h(dv),:].Wv[dv,:] + bv[dv] ----------------
__global__ __launch_bounds__(256) void pooled_kernel(
    const float* __restrict__ xbar, const float* __restrict__ Wv,
    const float* __restrict__ bv, float* __restrict__ pooled) {
  const int lane = threadIdx.x & 63;
  const int dv = blockIdx.x * 4 + (threadIdx.x >> 6);
  const int h = dv >> 8;  // dv / DK_
  const float* wrow = Wv + (size_t)dv * D_;
  const float* x0 = xbar + (size_t)h * D_;
  const float* x1 = xbar + (size_t)(H_ + h) * D_;
  float a0 = 0.f, a1 = 0.f;
  for (int c = lane; c < D_; c += 64) {
    float wv = wrow[c];
    a0 += wv * x0[c];
    a1 += wv * x1[c];
  }
  for (int m = 1; m < 64; m <<= 1) { a0 += __shfl_xor(a0, m); a1 += __shfl_xor(a1, m); }
  if (lane == 0) {
    float bb = bv[dv];
    pooled[dv] = a0 + bb;
    pooled[D_ + dv] = a1 + bb;
  }
}

// ---------------- out[b,n] = tanh(pooled[b,:].Wp[n,:] + bp[n]) ----------------
__global__ __launch_bounds__(256) void final_kernel(
    const float* __restrict__ pooled, const float* __restrict__ Wp,
    const float* __restrict__ bp, float* __restrict__ out) {
  const int lane = threadIdx.x & 63;
  const int n = blockIdx.x * 4 + (threadIdx.x >> 6);
  const float* wrow = Wp + (size_t)n * D_;
  float a0 = 0.f, a1 = 0.f;
  for (int c = lane; c < D_; c += 64) {
    float wv = wrow[c];
    a0 += wv * pooled[c];
    a1 += wv * pooled[D_ + c];
  }
  for (int m = 1; m < 64; m <<= 1) { a0 += __shfl_xor(a0, m); a1 += __shfl_xor(a1, m); }
  if (lane == 0) {
    float bb = bp[n];
    out[n] = tanhf(a0 + bb);
    out[D_ + n] = tanhf(a1 + bb);
  }
}

extern "C" void kernel_launch(void* const* d_in, const int* in_sizes, int n_in,
                              void* d_out, int out_size, void* d_ws, size_t ws_size,
                              hipStream_t stream) {
  const float* x = (const float*)d_in[0];
  const int* xmask = (const int*)d_in[1];
  const float* Wq = (const float*)d_in[2];
  const float* bq = (const float*)d_in[3];
  const float* Wk = (const float*)d_in[4];
  const float* bk = (const float*)d_in[5];
  const float* Wv = (const float*)d_in[6];
  const float* bv = (const float*)d_in[7];
  const float* Wa = (const float*)d_in[8];
  const float* ba = (const float*)d_in[9];
  const float* Wp = (const float*)d_in[10];
  const float* bp = (const float*)d_in[11];
  float* out = (float*)d_out;

  char* ws = (char*)d_ws;
  bf16* Xb = (bf16*)ws;    ws += (size_t)B_ * S_ * D_ * 2;
  bf16* Wqb = (bf16*)ws;   ws += (size_t)D_ * D_ * 2;
  bf16* Wkb = (bf16*)ws;   ws += (size_t)D_ * D_ * 2;
  bf16* Qb = (bf16*)ws;    ws += (size_t)B_ * S_ * D_ * 2;
  bf16* Kbf = (bf16*)ws;   ws += (size_t)B_ * S_ * D_ * 2;
  float* score = (float*)ws;  ws += (size_t)B_ * H_ * S_ * 4;
  float* attn = (float*)ws;   ws += (size_t)B_ * H_ * S_ * 4;
  float* xbar = (float*)ws;   ws += (size_t)B_ * H_ * D_ * 4;
  float* pooled = (float*)ws; ws += (size_t)B_ * D_ * 4;

  const int nX4 = B_ * S_ * D_ / 4, nW4 = D_ * D_ / 4;
  cvt_kernel<<<nX4 / 256, 256, 0, stream>>>(x, Xb, nX4);
  cvt_kernel<<<nW4 / 256, 256, 0, stream>>>(Wq, Wqb, nW4);
  cvt_kernel<<<nW4 / 256, 256, 0, stream>>>(Wk, Wkb, nW4);

  gemm_qk<<<dim3(D_ / 128, B_ * S_ / 128, 2), 256, 0, stream>>>(
      Xb, Wqb, bq, Qb, Wkb, bk, Kbf);

  hipMemsetAsync(score, 0, (size_t)B_ * H_ * S_ * 4, stream);
  score_kernel<<<dim3(S_ / 128, 2, B_ * H_), 256, 0, stream>>>(Qb, Kbf, Wa, score);

  softmax_kernel<<<B_ * H_, 256, 0, stream>>>(score, xmask, ba, attn);

  hipMemsetAsync(xbar, 0, (size_t)B_ * H_ * D_ * 4, stream);
  xbar_kernel<<<dim3(8, 4, B_), 256, 0, stream>>>(x, attn, xbar);

  pooled_kernel<<<D_ / 4, 256, 0, stream>>>(xbar, Wv, bv, pooled);
  final_kernel<<<D_ / 4, 256, 0, stream>>>(pooled, Wp, bp, out);
}

// Round 4
// 373.709 us; speedup vs baseline: 1.1016x; 1.1016x over previous
//
#include <hip/hip_runtime.h>
#include <hip/hip_bf16.h>
#include <stdint.h>

#define B_ 2
#define S_ 2048
#define D_ 2048
#define H_ 8
#define DK_ 256
#define SCALE_ 0.0625f
#define NEG_ -1e9f

typedef __hip_bfloat16 bf16;
typedef __attribute__((ext_vector_type(4))) float f32x4;
typedef __attribute__((ext_vector_type(8))) short bf16x8;
typedef unsigned int u32;

__device__ inline void gload_lds16(const void* g, void* l) {
  __builtin_amdgcn_global_load_lds(
      (const __attribute__((address_space(1))) u32*)g,
      (__attribute__((address_space(3))) u32*)l, 16, 0, 0);
}

// ---------------- fp32 -> bf16 convert (vectorized) ----------------
__global__ void cvt_kernel(const float* __restrict__ in, bf16* __restrict__ out, int n4) {
  int i = blockIdx.x * 256 + threadIdx.x;
  if (i >= n4) return;
  float4 v = ((const float4*)in)[i];
  ushort4 o;
  o.x = __builtin_bit_cast(unsigned short, __float2bfloat16(v.x));
  o.y = __builtin_bit_cast(unsigned short, __float2bfloat16(v.y));
  o.z = __builtin_bit_cast(unsigned short, __float2bfloat16(v.z));
  o.w = __builtin_bit_cast(unsigned short, __float2bfloat16(v.w));
  ((ushort4*)out)[i] = o;
}

// ---------------- fused Q/K projection GEMM (m97 structure) ----------------
// C = A[M,K] @ W[N,K]^T + bias, stored bf16 HEAD-MAJOR: C[b,h,s,dk].
__global__ __launch_bounds__(256, 2) void gemm_qk(
    const bf16* __restrict__ A,
    const bf16* __restrict__ W0, const float* __restrict__ b0, bf16* __restrict__ C0,
    const bf16* __restrict__ W1, const float* __restrict__ b1, bf16* __restrict__ C1) {
  const int Kd = D_;
  const bf16* Bm = blockIdx.z ? W1 : W0;
  const float* bias = blockIdx.z ? b1 : b0;
  bf16* C = blockIdx.z ? C1 : C0;

  __shared__ bf16 As[128 * 64];
  __shared__ bf16 Bs[128 * 64];
  const int tid = threadIdx.x;
  const int lane = tid & 63;
  const int w = tid >> 6;
  const int wr = w >> 1, wc = w & 1;
  const int bm = blockIdx.y, bn = blockIdx.x;

  f32x4 acc[4][4] = {};
  const int l8r = lane >> 3;        // 0..7 row within 8-row chunk
  const int l8c = (lane & 7) * 8;   // k element offset (8 bf16 = 16B)

  for (int kt = 0; kt < Kd; kt += 64) {
#pragma unroll
    for (int cc = 0; cc < 4; ++cc) {
      int chunk = w * 4 + cc;                       // 0..15
      int rowa = bm * 128 + chunk * 8 + l8r;
      gload_lds16(A + (size_t)rowa * Kd + kt + l8c, (char*)As + chunk * 1024);
      int rowb = bn * 128 + chunk * 8 + l8r;
      gload_lds16(Bm + (size_t)rowb * Kd + kt + l8c, (char*)Bs + chunk * 1024);
    }
    __syncthreads();
#pragma unroll
    for (int kk = 0; kk < 2; ++kk) {
      const int kloc = kk * 32 + (lane >> 4) * 8;
      bf16x8 af[4], bfr[4];
#pragma unroll
      for (int mi = 0; mi < 4; ++mi) {
        int row = wr * 64 + mi * 16 + (lane & 15);
        af[mi] = *(const bf16x8*)&As[row * 64 + kloc];
      }
#pragma unroll
      for (int ni = 0; ni < 4; ++ni) {
        int row = wc * 64 + ni * 16 + (lane & 15);
        bfr[ni] = *(const bf16x8*)&Bs[row * 64 + kloc];
      }
#pragma unroll
      for (int mi = 0; mi < 4; ++mi)
#pragma unroll
        for (int ni = 0; ni < 4; ++ni)
          acc[mi][ni] = __builtin_amdgcn_mfma_f32_16x16x32_bf16(af[mi], bfr[ni], acc[mi][ni], 0, 0, 0);
    }
    __syncthreads();
  }
  // epilogue: C layout col=lane&15, row=(lane>>4)*4+r ; store head-major
#pragma unroll
  for (int ni = 0; ni < 4; ++ni) {
    int col = bn * 128 + wc * 64 + ni * 16 + (lane & 15);
    int h = col >> 8, dk = col & 255;
    float bb = bias[col];
#pragma unroll
    for (int mi = 0; mi < 4; ++mi) {
      int rbase = bm * 128 + wr * 64 + mi * 16 + (lane >> 4) * 4;
#pragma unroll
      for (int r = 0; r < 4; ++r) {
        int row = rbase + r;
        int b = row >> 11, s = row & 2047;
        C[(((size_t)b * H_ + h) * S_ + s) * DK_ + dk] = __float2bfloat16(acc[mi][ni][r] + bb);
      }
    }
  }
}

// ---------------- score kernel: score[bh,i] = sum_j lrelu(q_i.k_j)*Wa[j] ----------------
// head-major Q/K [bh, S, DK]; grid (16 bh, 16 it).
// 256 thr = 4 waves 2x2 (64i x 64j); each block loops all 16 j-tiles, dbuf K in LDS.
__global__ __launch_bounds__(256, 1) void score_kernel(
    const bf16* __restrict__ Qh, const bf16* __restrict__ Kh,
    const float* __restrict__ Wa, float* __restrict__ score) {
  __shared__ bf16 Ks[2][128 * 256];  // 2 x 64KB, XOR-swizzled rows (512B rows)
  __shared__ float sred[2][128];     // cross-wave (wc) partial sums
  const int tid = threadIdx.x, lane = tid & 63, w = tid >> 6;
  const int wr = w >> 1, wc = w & 1;
  const int bh = blockIdx.x;
  const int it = blockIdx.y;

  const bf16* Qbase = Qh + (size_t)bh * S_ * DK_;
  const bf16* Kbase = Kh + (size_t)bh * S_ * DK_;

  // Q fragments held in registers, reused over all j tiles
  bf16x8 qf[4][8];
#pragma unroll
  for (int mi = 0; mi < 4; ++mi) {
    int row = it * 128 + wr * 64 + mi * 16 + (lane & 15);
    const bf16* qp = Qbase + (size_t)row * DK_ + ((lane >> 4) * 8);
#pragma unroll
    for (int kc = 0; kc < 8; ++kc) qf[mi][kc] = *(const bf16x8*)(qp + kc * 32);
  }

  const int stg_r_sub = lane >> 5;          // 0..1
  const int stg_b = (lane & 31) * 16;       // byte within 512B row
  auto STAGE = [&](int buf, int jt) {
    const char* src = (const char*)(Kbase + (size_t)jt * 128 * DK_);
#pragma unroll
    for (int cc = 0; cc < 16; ++cc) {
      int chunk = w * 16 + cc;              // 0..63, 1KB each (2 rows)
      int r = chunk * 2 + stg_r_sub;
      int gb = stg_b ^ ((r & 7) << 4);      // pre-swizzled source byte
      gload_lds16(src + (size_t)r * 512 + gb, (char*)&Ks[buf][0] + chunk * 1024);
    }
  };

  STAGE(0, 0);
  __syncthreads();

  float psum[4][4] = {};
  for (int jt = 0; jt < 16; ++jt) {
    const int cur = jt & 1;
    if (jt + 1 < 16) STAGE(cur ^ 1, jt + 1);
    const char* Kc = (const char*)&Ks[cur][0];
#pragma unroll
    for (int nj = 0; nj < 4; ++nj) {
      int jloc = wc * 64 + nj * 16 + (lane & 15);
      bf16x8 bfr[8];
#pragma unroll
      for (int kc = 0; kc < 8; ++kc) {
        int kbyte = (kc * 32 + ((lane >> 4) * 8)) * 2;
        bfr[kc] = *(const bf16x8*)(Kc + jloc * 512 + (kbyte ^ ((jloc & 7) << 4)));
      }
      f32x4 cf[4] = {};
#pragma unroll
      for (int kc = 0; kc < 8; ++kc)
#pragma unroll
        for (int mi = 0; mi < 4; ++mi)
          cf[mi] = __builtin_amdgcn_mfma_f32_16x16x32_bf16(qf[mi][kc], bfr[kc], cf[mi], 0, 0, 0);
      float wa = Wa[jt * 128 + jloc];
#pragma unroll
      for (int mi = 0; mi < 4; ++mi)
#pragma unroll
        for (int r = 0; r < 4; ++r) {
          float v = cf[mi][r];
          v = (v > 0.f) ? v : 0.1f * v;   // leaky_relu 0.1
          psum[mi][r] += v * wa;
        }
    }
    __syncthreads();  // drains vmcnt(0): next tile landed, all reads of cur done
  }
  // lane-group reduce: lanes 0..15 of each 16-group hold different j columns
#pragma unroll
  for (int mi = 0; mi < 4; ++mi)
#pragma unroll
    for (int r = 0; r < 4; ++r) {
      float v = psum[mi][r];
      v += __shfl_xor(v, 1); v += __shfl_xor(v, 2);
      v += __shfl_xor(v, 4); v += __shfl_xor(v, 8);
      if ((lane & 15) == 0) {
        int lrow = wr * 64 + mi * 16 + ((lane >> 4) * 4) + r;  // 0..127
        sred[wc][lrow] = v;   // each wc-wave covers half the j columns
      }
    }
  __syncthreads();
  if (tid < 128)
    score[(size_t)bh * S_ + it * 128 + tid] = sred[0][tid] + sred[1][tid];
}

// ---------------- masked scaled softmax over tokens ----------------
__global__ __launch_bounds__(256) void softmax_kernel(
    const float* __restrict__ score, const int* __restrict__ xmask,
    const float* __restrict__ ba, float* __restrict__ attn) {
  const int bh = blockIdx.x, tid = threadIdx.x;
  const int lane = tid & 63, w = tid >> 6;
  __shared__ float redm[4], reds[4];
  const float ba0 = ba[0];
  float loc[8];
  float mx = -3.4e38f;
#pragma unroll
  for (int t = 0; t < 8; ++t) {
    int i = t * 256 + tid;
    float s = SCALE_ * (score[(size_t)bh * S_ + i] + ba0);
    if (xmask[i] != 0) s = NEG_;
    loc[t] = s;
    mx = fmaxf(mx, s);
  }
  for (int m = 1; m < 64; m <<= 1) mx = fmaxf(mx, __shfl_xor(mx, m));
  if (lane == 0) redm[w] = mx;
  __syncthreads();
  mx = fmaxf(fmaxf(redm[0], redm[1]), fmaxf(redm[2], redm[3]));
  float sum = 0.f;
#pragma unroll
  for (int t = 0; t < 8; ++t) {
    loc[t] = expf(loc[t] - mx);
    sum += loc[t];
  }
  for (int m = 1; m < 64; m <<= 1) sum += __shfl_xor(sum, m);
  if (lane == 0) reds[w] = sum;
  __syncthreads();
  sum = reds[0] + reds[1] + reds[2] + reds[3];
  const float inv = 1.f / sum;
#pragma unroll
  for (int t = 0; t < 8; ++t) attn[(size_t)bh * S_ + t * 256 + tid] = loc[t] * inv;
}

// ---------------- xbar[b,h,c] = sum_s attn[b,h,s] * x[b,s,c] ----------------
// grid (2 c-blocks, 64 s-blocks, B); thread owns 4 consecutive c (float4)
__global__ __launch_bounds__(256) void xbar_kernel(
    const float* __restrict__ x, const float* __restrict__ attn, float* __restrict__ xbar) {
  const int cblk = blockIdx.x, sblk = blockIdx.y, b = blockIdx.z;
  const int tid = threadIdx.x;
  const int c = cblk * 1024 + tid * 4;
  __shared__ float at_s[8][32];
  for (int i = tid; i < 8 * 32; i += 256) {
    int h = i >> 5, s = i & 31;
    at_s[h][s] = attn[((size_t)b * H_ + h) * S_ + sblk * 32 + s];
  }
  __syncthreads();
  float acc[8][4] = {};
  const float* xp = x + ((size_t)b * S_ + sblk * 32) * D_ + c;
#pragma unroll 8
  for (int s = 0; s < 32; ++s) {
    float4 xv = *(const float4*)(xp + (size_t)s * D_);
#pragma unroll
    for (int h = 0; h < 8; ++h) {
      float a = at_s[h][s];
      acc[h][0] += a * xv.x; acc[h][1] += a * xv.y;
      acc[h][2] += a * xv.z; acc[h][3] += a * xv.w;
    }
  }
#pragma unroll
  for (int h = 0; h < 8; ++h)
#pragma unroll
    for (int e = 0; e < 4; ++e)
      atomicAdd(&xbar[((size_t)b * H_ + h) * D_ + c + e], acc[h][e]);
}

// ---------------- pooled[b,dv] = xbar[b,h(dv),:].Wv[dv,:] + bv[dv] ----------------
__global__ __launch_bounds__(256) void pooled_kernel(
    const float* __restrict__ xbar, const float* __restrict__ Wv,
    const float* __restrict__ bv, float* __restrict__ pooled) {
  const int lane = threadIdx.x & 63;
  const int dv = blockIdx.x * 4 + (threadIdx.x >> 6);
  const int h = dv >> 8;  // dv / DK_
  const float* wrow = Wv + (size_t)dv * D_;
  const float* x0 = xbar + (size_t)h * D_;
  const float* x1 = xbar + (size_t)(H_ + h) * D_;
  float a0 = 0.f, a1 = 0.f;
  for (int c = lane; c < D_; c += 64) {
    float wv = wrow[c];
    a0 += wv * x0[c];
    a1 += wv * x1[c];
  }
  for (int m = 1; m < 64; m <<= 1) { a0 += __shfl_xor(a0, m); a1 += __shfl_xor(a1, m); }
  if (lane == 0) {
    float bb = bv[dv];
    pooled[dv] = a0 + bb;
    pooled[D_ + dv] = a1 + bb;
  }
}

// ---------------- out[b,n] = tanh(pooled[b,:].Wp[n,:] + bp[n]) ----------------
__global__ __launch_bounds__(256) void final_kernel(
    const float* __restrict__ pooled, const float* __restrict__ Wp,
    const float* __restrict__ bp, float* __restrict__ out) {
  const int lane = threadIdx.x & 63;
  const int n = blockIdx.x * 4 + (threadIdx.x >> 6);
  const float* wrow = Wp + (size_t)n * D_;
  float a0 = 0.f, a1 = 0.f;
  for (int c = lane; c < D_; c += 64) {
    float wv = wrow[c];
    a0 += wv * pooled[c];
    a1 += wv * pooled[D_ + c];
  }
  for (int m = 1; m < 64; m <<= 1) { a0 += __shfl_xor(a0, m); a1 += __shfl_xor(a1, m); }
  if (lane == 0) {
    float bb = bp[n];
    out[n] = tanhf(a0 + bb);
    out[D_ + n] = tanhf(a1 + bb);
  }
}

extern "C" void kernel_launch(void* const* d_in, const int* in_sizes, int n_in,
                              void* d_out, int out_size, void* d_ws, size_t ws_size,
                              hipStream_t stream) {
  const float* x = (const float*)d_in[0];
  const int* xmask = (const int*)d_in[1];
  const float* Wq = (const float*)d_in[2];
  const float* bq = (const float*)d_in[3];
  const float* Wk = (const float*)d_in[4];
  const float* bk = (const float*)d_in[5];
  const float* Wv = (const float*)d_in[6];
  const float* bv = (const float*)d_in[7];
  const float* Wa = (const float*)d_in[8];
  const float* ba = (const float*)d_in[9];
  const float* Wp = (const float*)d_in[10];
  const float* bp = (const float*)d_in[11];
  float* out = (float*)d_out;

  char* ws = (char*)d_ws;
  bf16* Xb = (bf16*)ws;    ws += (size_t)B_ * S_ * D_ * 2;
  bf16* Wqb = (bf16*)ws;   ws += (size_t)D_ * D_ * 2;
  bf16* Wkb = (bf16*)ws;   ws += (size_t)D_ * D_ * 2;
  bf16* Qb = (bf16*)ws;    ws += (size_t)B_ * S_ * D_ * 2;   // head-major [bh,S,DK]
  bf16* Kbf = (bf16*)ws;   ws += (size_t)B_ * S_ * D_ * 2;   // head-major [bh,S,DK]
  float* score = (float*)ws;  ws += (size_t)B_ * H_ * S_ * 4;
  float* attn = (float*)ws;   ws += (size_t)B_ * H_ * S_ * 4;
  float* xbar = (float*)ws;   ws += (size_t)B_ * H_ * D_ * 4;
  float* pooled = (float*)ws; ws += (size_t)B_ * D_ * 4;

  const int nX4 = B_ * S_ * D_ / 4, nW4 = D_ * D_ / 4;
  cvt_kernel<<<nX4 / 256, 256, 0, stream>>>(x, Xb, nX4);
  cvt_kernel<<<nW4 / 256, 256, 0, stream>>>(Wq, Wqb, nW4);
  cvt_kernel<<<nW4 / 256, 256, 0, stream>>>(Wk, Wkb, nW4);

  gemm_qk<<<dim3(D_ / 128, B_ * S_ / 128, 2), 256, 0, stream>>>(
      Xb, Wqb, bq, Qb, Wkb, bk, Kbf);

  score_kernel<<<dim3(B_ * H_, S_ / 128), 256, 0, stream>>>(Qb, Kbf, Wa, score);

  softmax_kernel<<<B_ * H_, 256, 0, stream>>>(score, xmask, ba, attn);

  hipMemsetAsync(xbar, 0, (size_t)B_ * H_ * D_ * 4, stream);
  xbar_kernel<<<dim3(2, 64, B_), 256, 0, stream>>>(x, attn, xbar);

  pooled_kernel<<<D_ / 4, 256, 0, stream>>>(xbar, Wv, bv, pooled);
  final_kernel<<<D_ / 4, 256, 0, stream>>>(pooled, Wp, bp, out);
}